// Round 5
// baseline (27.363 us; speedup 1.0000x reference)
//
#include <hip/hip_runtime.h>
#include <hip/hip_bf16.h>

// DiffJPEG fused, v5: concurrent Y/chroma waves, direct register stores.
// Strip = 16x128 px. 384 threads = 6 waves:
//   waves 0-3 (tid 0..255)  : Y block-rows. blk=(tid>>6)*8+(lane&7), row=lane>>3.
//   wave 4    (tid 256..319): Cb block-rows (8 blocks x 8 rows).
//   wave 5    (tid 320..383): Cr block-rows.
// P0: Y threads load RGB, convert, 2x2-pool sums -> PL (LDS). barrier.
// P1: Y waves transform in registers || chroma waves: PL -> transform -> CL. barrier.
// P2: Y threads read CL (conflict-free stride-65 scalars), combine, store.
// LDS ~11.4 KB, all scalar access patterns conflict-free or 2-way.

__device__ constexpr float YTAB8[8][8] = {   // = _Y transposed (Y_TABLE)
    {16, 12, 14, 14, 18, 24, 49, 72},
    {11, 12, 13, 17, 22, 35, 64, 92},
    {10, 14, 16, 22, 37, 55, 78, 95},
    {16, 19, 24, 29, 56, 64, 87, 98},
    {24, 26, 40, 51, 68, 81, 103, 112},
    {40, 58, 57, 87, 109, 104, 121, 100},
    {51, 60, 69, 80, 103, 113, 120, 103},
    {61, 55, 56, 62, 77, 92, 101, 99}};

__device__ constexpr float CTAB8[8][8] = {
    {17, 18, 24, 47, 99, 99, 99, 99},
    {18, 21, 26, 66, 99, 99, 99, 99},
    {24, 26, 56, 99, 99, 99, 99, 99},
    {47, 66, 99, 99, 99, 99, 99, 99},
    {99, 99, 99, 99, 99, 99, 99, 99},
    {99, 99, 99, 99, 99, 99, 99, 99},
    {99, 99, 99, 99, 99, 99, 99, 99},
    {99, 99, 99, 99, 99, 99, 99, 99}};

#define C1f 0.9807852804032304f
#define C2f 0.9238795325112867f
#define C3f 0.8314696123025452f
#define C4f 0.7071067811865476f
#define C5f 0.5555702330196022f
#define C6f 0.3826834323650898f
#define C7f 0.1950903220161283f

__device__ __forceinline__ void dct8(float y[8]) {
    float e0=y[0]+y[7], e1=y[1]+y[6], e2=y[2]+y[5], e3=y[3]+y[4];
    float o0=y[0]-y[7], o1=y[1]-y[6], o2=y[2]-y[5], o3=y[3]-y[4];
    float t0=e0+e3, t1=e1+e2, d0=e0-e3, d1=e1-e2;
    y[0]=t0+t1; y[4]=(t0-t1)*C4f;
    y[2]=d0*C2f+d1*C6f; y[6]=d0*C6f-d1*C2f;
    y[1]=o0*C1f+o1*C3f+o2*C5f+o3*C7f;
    y[3]=o0*C3f-o1*C7f-o2*C1f-o3*C5f;
    y[5]=o0*C5f-o1*C1f+o2*C7f+o3*C3f;
    y[7]=o0*C7f-o1*C5f+o2*C3f-o3*C1f;
}

__device__ __forceinline__ void idct8(float y[8]) {
    float a=y[4]*C4f, p=y[0]+a, m=y[0]-a;
    float q=y[2]*C2f+y[6]*C6f, w=y[2]*C6f-y[6]*C2f;
    float E0=p+q, E1=m+w, E2=m-w, E3=p-q;
    float O0=y[1]*C1f+y[3]*C3f+y[5]*C5f+y[7]*C7f;
    float O1=y[1]*C3f-y[3]*C7f-y[5]*C1f-y[7]*C5f;
    float O2=y[1]*C5f-y[3]*C1f+y[5]*C7f+y[7]*C3f;
    float O3=y[1]*C7f-y[3]*C5f+y[5]*C3f-y[7]*C1f;
    y[0]=E0+O0; y[7]=E0-O0; y[1]=E1+O1; y[6]=E1-O1;
    y[2]=E2+O2; y[5]=E2-O2; y[3]=E3+O3; y[4]=E3-O3;
}

// 8x8 transpose across the 8 threads (lane bits 3..5) holding one block.
__device__ __forceinline__ void transpose8(float y[8]) {
    const int lane = threadIdx.x & 63;
#pragma unroll
    for (int s = 1; s <= 4; s <<= 1) {
        const bool upper = (lane & (s << 3)) != 0;
#pragma unroll
        for (int j = 0; j < 8; ++j) {
            if ((j & s) == 0) {
                float a = y[j], b2 = y[j | s];
                float t = upper ? a : b2;
                t = __shfl_xor(t, s << 3, 64);
                if (upper) y[j] = t; else y[j | s] = t;
            }
        }
    }
}

__device__ __forceinline__ float diff_round_f(float x) {
    float f = x - rintf(x);
    float th = 6.283185307179586f * f;
    float s1, c1v;
    __sincosf(th, &s1, &c1v);
    float twoc = 2.0f * c1v;
    float sp = 0.0f, sc = s1, acc = 0.0f;
    const float coef[9] = {1.0f, -0.5f, 1.0f/3.0f, -0.25f, 0.2f,
                           -1.0f/6.0f, 1.0f/7.0f, -0.125f, 1.0f/9.0f};
#pragma unroll
    for (int n = 0; n < 9; ++n) {
        acc += coef[n] * sc;
        float sn = twoc * sc - sp;
        sp = sc; sc = sn;
    }
    return x - acc * 0.3183098861837907f;
}

__global__ __launch_bounds__(384, 6) void diffjpeg_kernel(
        const float* __restrict__ x, float* __restrict__ out) {
    __shared__ float QS[2][128];     // (s1,s2) interleaved; [0]=Y, [1]=C
    __shared__ float PL[3][8][65];   // pooled RGB sums [ch][prow][pcol], stride 65
    __shared__ float CL[2][8][65];   // decompressed chroma, stride 65

    const int tid = threadIdx.x;
    const int lane = tid & 63;
    const int r = lane >> 3;
    const int b = lane & 7;

    if (tid < 128) {
        int type = tid >> 6;
        int k = tid & 63, u = k >> 3, v = k & 7;
        float t = (type ? CTAB8[u][v] : YTAB8[u][v]) * 0.1f;
        float aa = 0.25f * ((u == 0) ? C4f : 1.0f) * ((v == 0) ? C4f : 1.0f);
        QS[type][2 * k]     = aa / t;
        QS[type][2 * k + 1] = aa * t;
    }

    const int img = blockIdx.y;
    const int sy = (blockIdx.x >> 2) * 16;
    const int sx = (blockIdx.x & 3) * 128;
    const size_t plane = (size_t)512 * 512;
    const float* src = x + (size_t)img * 3 * plane;
    float* dst = out + (size_t)img * 3 * plane;

    float y[8];
    const int w = tid >> 6;
    const int brow = w >> 1;                 // Y threads only
    const int bcol = (w & 1) * 8 + b;

    // ---- P0: Y threads load one block-row, convert, pool ----
    if (tid < 256) {
        const int py = sy + brow * 8 + r;
        const int px = sx + bcol * 8;
        const float* p = src + (size_t)py * 512 + px;
        float4 R0 = *(const float4*)(p);
        float4 R1 = *(const float4*)(p + 4);
        float4 G0 = *(const float4*)(p + plane);
        float4 G1 = *(const float4*)(p + plane + 4);
        float4 B0 = *(const float4*)(p + 2 * plane);
        float4 B1 = *(const float4*)(p + 2 * plane + 4);
        y[0] = 76.245f * R0.x + 149.685f * G0.x + 29.07f * B0.x - 128.0f;
        y[1] = 76.245f * R0.y + 149.685f * G0.y + 29.07f * B0.y - 128.0f;
        y[2] = 76.245f * R0.z + 149.685f * G0.z + 29.07f * B0.z - 128.0f;
        y[3] = 76.245f * R0.w + 149.685f * G0.w + 29.07f * B0.w - 128.0f;
        y[4] = 76.245f * R1.x + 149.685f * G1.x + 29.07f * B1.x - 128.0f;
        y[5] = 76.245f * R1.y + 149.685f * G1.y + 29.07f * B1.y - 128.0f;
        y[6] = 76.245f * R1.z + 149.685f * G1.z + 29.07f * B1.z - 128.0f;
        y[7] = 76.245f * R1.w + 149.685f * G1.w + 29.07f * B1.w - 128.0f;
        float rs0 = R0.x + R0.y, rs1 = R0.z + R0.w, rs2 = R1.x + R1.y, rs3 = R1.z + R1.w;
        float gs0 = G0.x + G0.y, gs1 = G0.z + G0.w, gs2 = G1.x + G1.y, gs3 = G1.z + G1.w;
        float bs0 = B0.x + B0.y, bs1 = B0.z + B0.w, bs2 = B1.x + B1.y, bs3 = B1.z + B1.w;
        rs0 += __shfl_xor(rs0, 8, 64); rs1 += __shfl_xor(rs1, 8, 64);
        rs2 += __shfl_xor(rs2, 8, 64); rs3 += __shfl_xor(rs3, 8, 64);
        gs0 += __shfl_xor(gs0, 8, 64); gs1 += __shfl_xor(gs1, 8, 64);
        gs2 += __shfl_xor(gs2, 8, 64); gs3 += __shfl_xor(gs3, 8, 64);
        bs0 += __shfl_xor(bs0, 8, 64); bs1 += __shfl_xor(bs1, 8, 64);
        bs2 += __shfl_xor(bs2, 8, 64); bs3 += __shfl_xor(bs3, 8, 64);
        if (!(r & 1)) {
            const int prow = brow * 4 + (r >> 1);
            const int pc = bcol * 4;
            PL[0][prow][pc] = rs0; PL[0][prow][pc+1] = rs1;
            PL[0][prow][pc+2] = rs2; PL[0][prow][pc+3] = rs3;
            PL[1][prow][pc] = gs0; PL[1][prow][pc+1] = gs1;
            PL[1][prow][pc+2] = gs2; PL[1][prow][pc+3] = gs3;
            PL[2][prow][pc] = bs0; PL[2][prow][pc+1] = bs1;
            PL[2][prow][pc+2] = bs2; PL[2][prow][pc+3] = bs3;
        }
    }
    __syncthreads();   // PL + QS ready

    // ---- P1: Y transform (waves 0-3) || chroma pipeline (waves 4-5) ----
    if (tid < 256) {
        dct8(y); transpose8(y); dct8(y);
        const float* qs = QS[0];
#pragma unroll
        for (int j = 0; j < 8; ++j) {
            float s1v = qs[2 * (j * 8 + r)];
            float s2v = qs[2 * (j * 8 + r) + 1];
            y[j] = diff_round_f(y[j] * s1v) * s2v;
        }
        idct8(y); transpose8(y); idct8(y);
        // y[j] = decompressed Y (no +128) at row brow*8+r, col bcol*8+j
    } else {
        const int ch = (tid >= 320);          // 0=Cb, 1=Cr
        const float kr = ch ?  31.875f   : -10.75692f;   // coeff * 255/4
        const float kg = ch ? -26.69136f : -21.11808f;
        const float kb = ch ?  -5.18364f :  31.875f;
        float c[8];
#pragma unroll
        for (int j = 0; j < 8; ++j)
            c[j] = kr * PL[0][r][b * 8 + j] + kg * PL[1][r][b * 8 + j]
                 + kb * PL[2][r][b * 8 + j];
        dct8(c); transpose8(c); dct8(c);
        const float* qs = QS[1];
#pragma unroll
        for (int j = 0; j < 8; ++j) {
            float s1v = qs[2 * (j * 8 + r)];
            float s2v = qs[2 * (j * 8 + r) + 1];
            c[j] = diff_round_f(c[j] * s1v) * s2v;
        }
        idct8(c); transpose8(c); idct8(c);
#pragma unroll
        for (int j = 0; j < 8; ++j)
            CL[ch][r][b * 8 + j] = c[j];
    }
    __syncthreads();   // CL ready

    // ---- P2: Y threads combine + store directly from registers ----
    if (tid < 256) {
        const int prow = brow * 4 + (r >> 1);
        const int pc = bcol * 4;
        float cbv[4], crv[4];
#pragma unroll
        for (int jj = 0; jj < 4; ++jj) {
            cbv[jj] = CL[0][prow][pc + jj];
            crv[jj] = CL[1][prow][pc + jj];
        }
        float oR[8], oG[8], oB[8];
#pragma unroll
        for (int j = 0; j < 8; ++j) {
            float cb = cbv[j >> 1], cr = crv[j >> 1];
            float yv = y[j] + 128.0f;
            float R = yv + 1.402f * cr;
            float G = yv - 0.344136f * cb - 0.714136f * cr;
            float B = yv + 1.772f * cb;
            oR[j] = fminf(fmaxf(R, 0.0f), 255.0f) * (1.0f / 255.0f);
            oG[j] = fminf(fmaxf(G, 0.0f), 255.0f) * (1.0f / 255.0f);
            oB[j] = fminf(fmaxf(B, 0.0f), 255.0f) * (1.0f / 255.0f);
        }
        const int py = sy + brow * 8 + r;
        const int px = sx + bcol * 8;
        float* p = dst + (size_t)py * 512 + px;
        *(float4*)(p)                 = make_float4(oR[0], oR[1], oR[2], oR[3]);
        *(float4*)(p + 4)             = make_float4(oR[4], oR[5], oR[6], oR[7]);
        *(float4*)(p + plane)         = make_float4(oG[0], oG[1], oG[2], oG[3]);
        *(float4*)(p + plane + 4)     = make_float4(oG[4], oG[5], oG[6], oG[7]);
        *(float4*)(p + 2 * plane)     = make_float4(oB[0], oB[1], oB[2], oB[3]);
        *(float4*)(p + 2 * plane + 4) = make_float4(oB[4], oB[5], oB[6], oB[7]);
    }
}

extern "C" void kernel_launch(void* const* d_in, const int* in_sizes, int n_in,
                              void* d_out, int out_size, void* d_ws, size_t ws_size,
                              hipStream_t stream) {
    const float* x = (const float*)d_in[0];
    float* out = (float*)d_out;
    dim3 grid(128, 16);   // 32x4 strips of 16x128 px per image, 16 images
    dim3 block(384);
    diffjpeg_kernel<<<grid, block, 0, stream>>>(x, out);
}

// Round 6
// 25.717 us; speedup vs baseline: 1.0640x; 1.0640x over previous
//
#include <hip/hip_runtime.h>

// DiffJPEG fused, v6: fully uniform work. Strip = 32x128 px, 256 threads.
// Every thread: 2 Y block-rows (blocks browA and browA+2) + 1 chroma block-row.
//   lane = r*8+b within wave w: Y blocks (browA=w>>1, bcol=(w&1)*8+b), row r.
//   chroma: ch=w>>1, block cbB=(w&1)*8+b (16 per channel in 16x64 pooled strip).
// P0: load 12 float4 (2 rows x RGB), convert Y, pool->chroma values -> PL.
// P1: 2 Y transforms + 1 chroma transform per thread (registers + shfl transposes).
// P2: combine + store both Y rows (32B contiguous per thread).
// LDS: QS 1KB + PL 8.3KB + CL 8.3KB = 17.6KB, stride-65 (conflict-free/2-way).

__device__ constexpr float YTAB8[8][8] = {   // = _Y transposed (Y_TABLE)
    {16, 12, 14, 14, 18, 24, 49, 72},
    {11, 12, 13, 17, 22, 35, 64, 92},
    {10, 14, 16, 22, 37, 55, 78, 95},
    {16, 19, 24, 29, 56, 64, 87, 98},
    {24, 26, 40, 51, 68, 81, 103, 112},
    {40, 58, 57, 87, 109, 104, 121, 100},
    {51, 60, 69, 80, 103, 113, 120, 103},
    {61, 55, 56, 62, 77, 92, 101, 99}};

__device__ constexpr float CTAB8[8][8] = {
    {17, 18, 24, 47, 99, 99, 99, 99},
    {18, 21, 26, 66, 99, 99, 99, 99},
    {24, 26, 56, 99, 99, 99, 99, 99},
    {47, 66, 99, 99, 99, 99, 99, 99},
    {99, 99, 99, 99, 99, 99, 99, 99},
    {99, 99, 99, 99, 99, 99, 99, 99},
    {99, 99, 99, 99, 99, 99, 99, 99},
    {99, 99, 99, 99, 99, 99, 99, 99}};

#define C1f 0.9807852804032304f
#define C2f 0.9238795325112867f
#define C3f 0.8314696123025452f
#define C4f 0.7071067811865476f
#define C5f 0.5555702330196022f
#define C6f 0.3826834323650898f
#define C7f 0.1950903220161283f

__device__ __forceinline__ void dct8(float y[8]) {
    float e0=y[0]+y[7], e1=y[1]+y[6], e2=y[2]+y[5], e3=y[3]+y[4];
    float o0=y[0]-y[7], o1=y[1]-y[6], o2=y[2]-y[5], o3=y[3]-y[4];
    float t0=e0+e3, t1=e1+e2, d0=e0-e3, d1=e1-e2;
    y[0]=t0+t1; y[4]=(t0-t1)*C4f;
    y[2]=d0*C2f+d1*C6f; y[6]=d0*C6f-d1*C2f;
    y[1]=o0*C1f+o1*C3f+o2*C5f+o3*C7f;
    y[3]=o0*C3f-o1*C7f-o2*C1f-o3*C5f;
    y[5]=o0*C5f-o1*C1f+o2*C7f+o3*C3f;
    y[7]=o0*C7f-o1*C5f+o2*C3f-o3*C1f;
}

__device__ __forceinline__ void idct8(float y[8]) {
    float a=y[4]*C4f, p=y[0]+a, m=y[0]-a;
    float q=y[2]*C2f+y[6]*C6f, w=y[2]*C6f-y[6]*C2f;
    float E0=p+q, E1=m+w, E2=m-w, E3=p-q;
    float O0=y[1]*C1f+y[3]*C3f+y[5]*C5f+y[7]*C7f;
    float O1=y[1]*C3f-y[3]*C7f-y[5]*C1f-y[7]*C5f;
    float O2=y[1]*C5f-y[3]*C1f+y[5]*C7f+y[7]*C3f;
    float O3=y[1]*C7f-y[3]*C5f+y[5]*C3f-y[7]*C1f;
    y[0]=E0+O0; y[7]=E0-O0; y[1]=E1+O1; y[6]=E1-O1;
    y[2]=E2+O2; y[5]=E2-O2; y[3]=E3+O3; y[4]=E3-O3;
}

// 8x8 transpose across the 8 threads (lane bits 3..5) holding one block.
__device__ __forceinline__ void transpose8(float y[8]) {
    const int lane = threadIdx.x & 63;
#pragma unroll
    for (int s = 1; s <= 4; s <<= 1) {
        const bool upper = (lane & (s << 3)) != 0;
#pragma unroll
        for (int j = 0; j < 8; ++j) {
            if ((j & s) == 0) {
                float a = y[j], b2 = y[j | s];
                float t = upper ? a : b2;
                t = __shfl_xor(t, s << 3, 64);
                if (upper) y[j] = t; else y[j | s] = t;
            }
        }
    }
}

// diff_round: f = fract(x) (period-1 reduction), hardware v_sin/v_cos take
// revolutions -> sin(2*pi*f), cos(2*pi*f) directly; Chebyshev recurrence for n=2..9.
__device__ __forceinline__ float diff_round_f(float x) {
    float f = __builtin_amdgcn_fractf(x);
    float sc = __builtin_amdgcn_sinf(f);
    float c1v = __builtin_amdgcn_cosf(f);
    float twoc = 2.0f * c1v;
    float sp = 0.0f, acc = 0.0f;
    const float coef[9] = {1.0f, -0.5f, 1.0f/3.0f, -0.25f, 0.2f,
                           -1.0f/6.0f, 1.0f/7.0f, -0.125f, 1.0f/9.0f};
#pragma unroll
    for (int n = 0; n < 9; ++n) {
        acc += coef[n] * sc;
        float sn = twoc * sc - sp;
        sp = sc; sc = sn;
    }
    return x - acc * 0.3183098861837907f;
}

// full per-block pipeline on the 8 values this thread holds (row r of block)
__device__ __forceinline__ void jpeg_block(float y[8], const float* qs, int r) {
    dct8(y); transpose8(y); dct8(y);
#pragma unroll
    for (int j = 0; j < 8; ++j) {
        float s1v = qs[2 * (j * 8 + r)];
        float s2v = qs[2 * (j * 8 + r) + 1];
        y[j] = diff_round_f(y[j] * s1v) * s2v;
    }
    idct8(y); transpose8(y); idct8(y);
}

__global__ __launch_bounds__(256, 4) void diffjpeg_kernel(
        const float* __restrict__ x, float* __restrict__ out) {
    __shared__ float QS[2][128];     // (s1,s2) interleaved; [0]=Y, [1]=C
    __shared__ float PL[2][16][65];  // pooled chroma (centered), [ch][prow][pcol]
    __shared__ float CL[2][16][65];  // decompressed chroma (centered)

    const int tid = threadIdx.x;
    const int lane = tid & 63;
    const int r = lane >> 3;
    const int b = lane & 7;
    const int w = tid >> 6;

    if (tid < 128) {
        int type = tid >> 6;
        int k = tid & 63, u = k >> 3, v = k & 7;
        float t = (type ? CTAB8[u][v] : YTAB8[u][v]) * 0.1f;
        float aa = 0.25f * ((u == 0) ? C4f : 1.0f) * ((v == 0) ? C4f : 1.0f);
        QS[type][2 * k]     = aa / t;
        QS[type][2 * k + 1] = aa * t;
    }

    const int img = blockIdx.y;
    const int sy = (blockIdx.x >> 2) * 32;
    const int sx = (blockIdx.x & 3) * 128;
    const size_t plane = (size_t)512 * 512;
    const float* src = x + (size_t)img * 3 * plane;
    float* dst = out + (size_t)img * 3 * plane;

    const int browA = w >> 1;                 // 0..1; block B = browA+2
    const int bcol  = (w & 1) * 8 + b;        // 0..15
    const int px  = sx + bcol * 8;
    const int pyA = sy + browA * 8 + r;
    const int pyB = pyA + 16;

    float yA[8], yB[8];
    {
        const float* pa = src + (size_t)pyA * 512 + px;
        const float* pb = src + (size_t)pyB * 512 + px;
        float4 RA0 = *(const float4*)(pa);
        float4 RA1 = *(const float4*)(pa + 4);
        float4 GA0 = *(const float4*)(pa + plane);
        float4 GA1 = *(const float4*)(pa + plane + 4);
        float4 BA0 = *(const float4*)(pa + 2 * plane);
        float4 BA1 = *(const float4*)(pa + 2 * plane + 4);
        float4 RB0 = *(const float4*)(pb);
        float4 RB1 = *(const float4*)(pb + 4);
        float4 GB0 = *(const float4*)(pb + plane);
        float4 GB1 = *(const float4*)(pb + plane + 4);
        float4 BB0 = *(const float4*)(pb + 2 * plane);
        float4 BB1 = *(const float4*)(pb + 2 * plane + 4);

        yA[0] = 76.245f*RA0.x + 149.685f*GA0.x + 29.07f*BA0.x - 128.0f;
        yA[1] = 76.245f*RA0.y + 149.685f*GA0.y + 29.07f*BA0.y - 128.0f;
        yA[2] = 76.245f*RA0.z + 149.685f*GA0.z + 29.07f*BA0.z - 128.0f;
        yA[3] = 76.245f*RA0.w + 149.685f*GA0.w + 29.07f*BA0.w - 128.0f;
        yA[4] = 76.245f*RA1.x + 149.685f*GA1.x + 29.07f*BA1.x - 128.0f;
        yA[5] = 76.245f*RA1.y + 149.685f*GA1.y + 29.07f*BA1.y - 128.0f;
        yA[6] = 76.245f*RA1.z + 149.685f*GA1.z + 29.07f*BA1.z - 128.0f;
        yA[7] = 76.245f*RA1.w + 149.685f*GA1.w + 29.07f*BA1.w - 128.0f;
        yB[0] = 76.245f*RB0.x + 149.685f*GB0.x + 29.07f*BB0.x - 128.0f;
        yB[1] = 76.245f*RB0.y + 149.685f*GB0.y + 29.07f*BB0.y - 128.0f;
        yB[2] = 76.245f*RB0.z + 149.685f*GB0.z + 29.07f*BB0.z - 128.0f;
        yB[3] = 76.245f*RB0.w + 149.685f*GB0.w + 29.07f*BB0.w - 128.0f;
        yB[4] = 76.245f*RB1.x + 149.685f*GB1.x + 29.07f*BB1.x - 128.0f;
        yB[5] = 76.245f*RB1.y + 149.685f*GB1.y + 29.07f*BB1.y - 128.0f;
        yB[6] = 76.245f*RB1.z + 149.685f*GB1.z + 29.07f*BB1.z - 128.0f;
        yB[7] = 76.245f*RB1.w + 149.685f*GB1.w + 29.07f*BB1.w - 128.0f;

        // horizontal pair sums -> chroma values (coeff * 255/4), both rows
        const float kbr = -10.75692f, kbg = -21.11808f, kbb = 31.875f;   // Cb
        const float krr =  31.875f,   krg = -26.69136f, krb = -5.18364f; // Cr
        float cbA[4], crA[4], cbB[4], crB[4];
        {
            float rh0=RA0.x+RA0.y, rh1=RA0.z+RA0.w, rh2=RA1.x+RA1.y, rh3=RA1.z+RA1.w;
            float gh0=GA0.x+GA0.y, gh1=GA0.z+GA0.w, gh2=GA1.x+GA1.y, gh3=GA1.z+GA1.w;
            float bh0=BA0.x+BA0.y, bh1=BA0.z+BA0.w, bh2=BA1.x+BA1.y, bh3=BA1.z+BA1.w;
            cbA[0]=kbr*rh0+kbg*gh0+kbb*bh0; cbA[1]=kbr*rh1+kbg*gh1+kbb*bh1;
            cbA[2]=kbr*rh2+kbg*gh2+kbb*bh2; cbA[3]=kbr*rh3+kbg*gh3+kbb*bh3;
            crA[0]=krr*rh0+krg*gh0+krb*bh0; crA[1]=krr*rh1+krg*gh1+krb*bh1;
            crA[2]=krr*rh2+krg*gh2+krb*bh2; crA[3]=krr*rh3+krg*gh3+krb*bh3;
        }
        {
            float rh0=RB0.x+RB0.y, rh1=RB0.z+RB0.w, rh2=RB1.x+RB1.y, rh3=RB1.z+RB1.w;
            float gh0=GB0.x+GB0.y, gh1=GB0.z+GB0.w, gh2=GB1.x+GB1.y, gh3=GB1.z+GB1.w;
            float bh0=BB0.x+BB0.y, bh1=BB0.z+BB0.w, bh2=BB1.x+BB1.y, bh3=BB1.z+BB1.w;
            cbB[0]=kbr*rh0+kbg*gh0+kbb*bh0; cbB[1]=kbr*rh1+kbg*gh1+kbb*bh1;
            cbB[2]=kbr*rh2+kbg*gh2+kbb*bh2; cbB[3]=kbr*rh3+kbg*gh3+kbb*bh3;
            crB[0]=krr*rh0+krg*gh0+krb*bh0; crB[1]=krr*rh1+krg*gh1+krb*bh1;
            crB[2]=krr*rh2+krg*gh2+krb*bh2; crB[3]=krr*rh3+krg*gh3+krb*bh3;
        }
        // vertical pair add: rows r and r^1 (lane bit 3)
#pragma unroll
        for (int k = 0; k < 4; ++k) {
            cbA[k] += __shfl_xor(cbA[k], 8, 64);
            crA[k] += __shfl_xor(crA[k], 8, 64);
            cbB[k] += __shfl_xor(cbB[k], 8, 64);
            crB[k] += __shfl_xor(crB[k], 8, 64);
        }
        if (!(r & 1)) {
            const int prowA = browA * 4 + (r >> 1);
            const int prowB = prowA + 8;
            const int pc = bcol * 4;
#pragma unroll
            for (int k = 0; k < 4; ++k) {
                PL[0][prowA][pc + k] = cbA[k];
                PL[1][prowA][pc + k] = crA[k];
                PL[0][prowB][pc + k] = cbB[k];
                PL[1][prowB][pc + k] = crB[k];
            }
        }
    }
    __syncthreads();   // PL + QS ready

    // ---- P1: two Y transforms + one chroma transform, all in registers ----
    jpeg_block(yA, QS[0], r);
    jpeg_block(yB, QS[0], r);

    {
        const int chw  = w >> 1;                // 0=Cb, 1=Cr
        const int cblk = (w & 1) * 8 + b;       // 0..15
        const int crow = (cblk >> 3) * 8 + r;   // 0..15
        const int ccol = (cblk & 7) * 8;        // 0..56
        float c[8];
#pragma unroll
        for (int j = 0; j < 8; ++j) c[j] = PL[chw][crow][ccol + j];
        jpeg_block(c, QS[1], r);
#pragma unroll
        for (int j = 0; j < 8; ++j) CL[chw][crow][ccol + j] = c[j];
    }
    __syncthreads();   // CL ready

    // ---- P2: combine + store both Y rows ----
    const int pc = bcol * 4;
#pragma unroll
    for (int blkI = 0; blkI < 2; ++blkI) {
        const float* yv8 = blkI ? yB : yA;
        const int prow = browA * 4 + (r >> 1) + blkI * 8;
        const int py   = blkI ? pyB : pyA;
        float cbv[4], crv[4];
#pragma unroll
        for (int jj = 0; jj < 4; ++jj) {
            cbv[jj] = CL[0][prow][pc + jj];
            crv[jj] = CL[1][prow][pc + jj];
        }
        float oR[8], oG[8], oB[8];
#pragma unroll
        for (int j = 0; j < 8; ++j) {
            float cb = cbv[j >> 1], cr = crv[j >> 1];
            float yv = yv8[j] + 128.0f;
            float R = yv + 1.402f * cr;
            float G = yv - 0.344136f * cb - 0.714136f * cr;
            float B = yv + 1.772f * cb;
            oR[j] = fminf(fmaxf(R, 0.0f), 255.0f) * (1.0f / 255.0f);
            oG[j] = fminf(fmaxf(G, 0.0f), 255.0f) * (1.0f / 255.0f);
            oB[j] = fminf(fmaxf(B, 0.0f), 255.0f) * (1.0f / 255.0f);
        }
        float* p = dst + (size_t)py * 512 + px;
        *(float4*)(p)                 = make_float4(oR[0], oR[1], oR[2], oR[3]);
        *(float4*)(p + 4)             = make_float4(oR[4], oR[5], oR[6], oR[7]);
        *(float4*)(p + plane)         = make_float4(oG[0], oG[1], oG[2], oG[3]);
        *(float4*)(p + plane + 4)     = make_float4(oG[4], oG[5], oG[6], oG[7]);
        *(float4*)(p + 2 * plane)     = make_float4(oB[0], oB[1], oB[2], oB[3]);
        *(float4*)(p + 2 * plane + 4) = make_float4(oB[4], oB[5], oB[6], oB[7]);
    }
}

extern "C" void kernel_launch(void* const* d_in, const int* in_sizes, int n_in,
                              void* d_out, int out_size, void* d_ws, size_t ws_size,
                              hipStream_t stream) {
    const float* x = (const float*)d_in[0];
    float* out = (float*)d_out;
    dim3 grid(64, 16);   // 16x4 strips of 32x128 px per image, 16 images
    dim3 block(256);
    diffjpeg_kernel<<<grid, block, 0, stream>>>(x, out);
}

// Round 7
// 24.875 us; speedup vs baseline: 1.1000x; 1.0338x over previous
//
#include <hip/hip_runtime.h>

// DiffJPEG fused, v7: single-wave workgroups for phase pipelining.
// Block = 1 wave (64 threads) = 16x32 px strip:
//   8 Y blocks (2 rows x 4 cols), lane (r=tid>>3, b=tid&7): Y block b, row r.
//   pooled chroma 8x16 = 2 Cb + 2 Cr blocks; lanes b<4 own them (b>=4 duplicate).
// No inter-wave coupling -> 8192 independent waves stream load/compute/store,
// keeping HBM busy while other waves compute (v4-v6 were generation-lockstepped).

__device__ constexpr float YTAB8[8][8] = {   // = _Y transposed (Y_TABLE)
    {16, 12, 14, 14, 18, 24, 49, 72},
    {11, 12, 13, 17, 22, 35, 64, 92},
    {10, 14, 16, 22, 37, 55, 78, 95},
    {16, 19, 24, 29, 56, 64, 87, 98},
    {24, 26, 40, 51, 68, 81, 103, 112},
    {40, 58, 57, 87, 109, 104, 121, 100},
    {51, 60, 69, 80, 103, 113, 120, 103},
    {61, 55, 56, 62, 77, 92, 101, 99}};

__device__ constexpr float CTAB8[8][8] = {
    {17, 18, 24, 47, 99, 99, 99, 99},
    {18, 21, 26, 66, 99, 99, 99, 99},
    {24, 26, 56, 99, 99, 99, 99, 99},
    {47, 66, 99, 99, 99, 99, 99, 99},
    {99, 99, 99, 99, 99, 99, 99, 99},
    {99, 99, 99, 99, 99, 99, 99, 99},
    {99, 99, 99, 99, 99, 99, 99, 99},
    {99, 99, 99, 99, 99, 99, 99, 99}};

#define C1f 0.9807852804032304f
#define C2f 0.9238795325112867f
#define C3f 0.8314696123025452f
#define C4f 0.7071067811865476f
#define C5f 0.5555702330196022f
#define C6f 0.3826834323650898f
#define C7f 0.1950903220161283f

__device__ __forceinline__ void dct8(float y[8]) {
    float e0=y[0]+y[7], e1=y[1]+y[6], e2=y[2]+y[5], e3=y[3]+y[4];
    float o0=y[0]-y[7], o1=y[1]-y[6], o2=y[2]-y[5], o3=y[3]-y[4];
    float t0=e0+e3, t1=e1+e2, d0=e0-e3, d1=e1-e2;
    y[0]=t0+t1; y[4]=(t0-t1)*C4f;
    y[2]=d0*C2f+d1*C6f; y[6]=d0*C6f-d1*C2f;
    y[1]=o0*C1f+o1*C3f+o2*C5f+o3*C7f;
    y[3]=o0*C3f-o1*C7f-o2*C1f-o3*C5f;
    y[5]=o0*C5f-o1*C1f+o2*C7f+o3*C3f;
    y[7]=o0*C7f-o1*C5f+o2*C3f-o3*C1f;
}

__device__ __forceinline__ void idct8(float y[8]) {
    float a=y[4]*C4f, p=y[0]+a, m=y[0]-a;
    float q=y[2]*C2f+y[6]*C6f, w=y[2]*C6f-y[6]*C2f;
    float E0=p+q, E1=m+w, E2=m-w, E3=p-q;
    float O0=y[1]*C1f+y[3]*C3f+y[5]*C5f+y[7]*C7f;
    float O1=y[1]*C3f-y[3]*C7f-y[5]*C1f-y[7]*C5f;
    float O2=y[1]*C5f-y[3]*C1f+y[5]*C7f+y[7]*C3f;
    float O3=y[1]*C7f-y[3]*C5f+y[5]*C3f-y[7]*C1f;
    y[0]=E0+O0; y[7]=E0-O0; y[1]=E1+O1; y[6]=E1-O1;
    y[2]=E2+O2; y[5]=E2-O2; y[3]=E3+O3; y[4]=E3-O3;
}

// 8x8 transpose across the 8 lanes (bits 3..5) holding one block.
__device__ __forceinline__ void transpose8(float y[8]) {
    const int lane = threadIdx.x & 63;
#pragma unroll
    for (int s = 1; s <= 4; s <<= 1) {
        const bool upper = (lane & (s << 3)) != 0;
#pragma unroll
        for (int j = 0; j < 8; ++j) {
            if ((j & s) == 0) {
                float a = y[j], b2 = y[j | s];
                float t = upper ? a : b2;
                t = __shfl_xor(t, s << 3, 64);
                if (upper) y[j] = t; else y[j | s] = t;
            }
        }
    }
}

// diff_round: hw v_fract (period-1 reduction) + hw v_sin/v_cos in revolutions,
// Chebyshev recurrence for harmonics 2..9.
__device__ __forceinline__ float diff_round_f(float x) {
    float f = __builtin_amdgcn_fractf(x);
    float sc = __builtin_amdgcn_sinf(f);
    float c1v = __builtin_amdgcn_cosf(f);
    float twoc = 2.0f * c1v;
    float sp = 0.0f, acc = 0.0f;
    const float coef[9] = {1.0f, -0.5f, 1.0f/3.0f, -0.25f, 0.2f,
                           -1.0f/6.0f, 1.0f/7.0f, -0.125f, 1.0f/9.0f};
#pragma unroll
    for (int n = 0; n < 9; ++n) {
        acc += coef[n] * sc;
        float sn = twoc * sc - sp;
        sp = sc; sc = sn;
    }
    return x - acc * 0.3183098861837907f;
}

__device__ __forceinline__ void jpeg_block(float y[8], const float* qs, int r) {
    dct8(y); transpose8(y); dct8(y);
#pragma unroll
    for (int j = 0; j < 8; ++j) {
        float s1v = qs[2 * (j * 8 + r)];
        float s2v = qs[2 * (j * 8 + r) + 1];
        y[j] = diff_round_f(y[j] * s1v) * s2v;
    }
    idct8(y); transpose8(y); idct8(y);
}

__global__ __launch_bounds__(64, 4) void diffjpeg_kernel(
        const float* __restrict__ x, float* __restrict__ out) {
    __shared__ float QS[2][128];     // (s1,s2) interleaved; [0]=Y, [1]=C
    __shared__ float PL[2][8][17];   // pooled chroma (centered), stride 17
    __shared__ float CL[2][8][17];   // decompressed chroma

    const int tid = threadIdx.x;     // 0..63
    const int r = tid >> 3;          // row within block / transpose group
    const int b = tid & 7;           // Y block index within strip

    // quant/dequant scales; each lane fills (u,v)=tid for both tables
    {
        const int u = r, v = b;
        float ty = YTAB8[u][v] * 0.1f;
        float tc = CTAB8[u][v] * 0.1f;
        float aa = 0.25f * ((u == 0) ? C4f : 1.0f) * ((v == 0) ? C4f : 1.0f);
        QS[0][2 * tid] = aa / ty; QS[0][2 * tid + 1] = aa * ty;
        QS[1][2 * tid] = aa / tc; QS[1][2 * tid + 1] = aa * tc;
    }

    const int img = blockIdx.y;
    const int sy = (blockIdx.x >> 4) * 16;
    const int sx = (blockIdx.x & 15) * 32;
    const size_t plane = (size_t)512 * 512;
    const float* src = x + (size_t)img * 3 * plane;
    float* dst = out + (size_t)img * 3 * plane;

    const int br = b >> 2, bc = b & 3;
    const int py = sy + br * 8 + r;
    const int px = sx + bc * 8;

    // ---- P0: load one Y block-row (RGB), convert, pool ----
    float y[8];
    {
        const float* p = src + (size_t)py * 512 + px;
        float4 R0 = *(const float4*)(p);
        float4 R1 = *(const float4*)(p + 4);
        float4 G0 = *(const float4*)(p + plane);
        float4 G1 = *(const float4*)(p + plane + 4);
        float4 B0 = *(const float4*)(p + 2 * plane);
        float4 B1 = *(const float4*)(p + 2 * plane + 4);
        y[0] = 76.245f*R0.x + 149.685f*G0.x + 29.07f*B0.x - 128.0f;
        y[1] = 76.245f*R0.y + 149.685f*G0.y + 29.07f*B0.y - 128.0f;
        y[2] = 76.245f*R0.z + 149.685f*G0.z + 29.07f*B0.z - 128.0f;
        y[3] = 76.245f*R0.w + 149.685f*G0.w + 29.07f*B0.w - 128.0f;
        y[4] = 76.245f*R1.x + 149.685f*G1.x + 29.07f*B1.x - 128.0f;
        y[5] = 76.245f*R1.y + 149.685f*G1.y + 29.07f*B1.y - 128.0f;
        y[6] = 76.245f*R1.z + 149.685f*G1.z + 29.07f*B1.z - 128.0f;
        y[7] = 76.245f*R1.w + 149.685f*G1.w + 29.07f*B1.w - 128.0f;
        // horizontal pair sums -> chroma (coeff*255/4; +-128 shift cancels)
        float rh0=R0.x+R0.y, rh1=R0.z+R0.w, rh2=R1.x+R1.y, rh3=R1.z+R1.w;
        float gh0=G0.x+G0.y, gh1=G0.z+G0.w, gh2=G1.x+G1.y, gh3=G1.z+G1.w;
        float bh0=B0.x+B0.y, bh1=B0.z+B0.w, bh2=B1.x+B1.y, bh3=B1.z+B1.w;
        const float kbr = -10.75692f, kbg = -21.11808f, kbb = 31.875f;   // Cb
        const float krr =  31.875f,   krg = -26.69136f, krb = -5.18364f; // Cr
        float cb[4], cr[4];
        cb[0]=kbr*rh0+kbg*gh0+kbb*bh0; cb[1]=kbr*rh1+kbg*gh1+kbb*bh1;
        cb[2]=kbr*rh2+kbg*gh2+kbb*bh2; cb[3]=kbr*rh3+kbg*gh3+kbb*bh3;
        cr[0]=krr*rh0+krg*gh0+krb*bh0; cr[1]=krr*rh1+krg*gh1+krb*bh1;
        cr[2]=krr*rh2+krg*gh2+krb*bh2; cr[3]=krr*rh3+krg*gh3+krb*bh3;
#pragma unroll
        for (int k = 0; k < 4; ++k) {   // vertical pair add (rows r, r^1)
            cb[k] += __shfl_xor(cb[k], 8, 64);
            cr[k] += __shfl_xor(cr[k], 8, 64);
        }
        if (!(r & 1)) {
            const int prow = br * 4 + (r >> 1);
            const int pc = bc * 4;
#pragma unroll
            for (int k = 0; k < 4; ++k) {
                PL[0][prow][pc + k] = cb[k];
                PL[1][prow][pc + k] = cr[k];
            }
        }
    }
    __syncthreads();   // PL + QS ready (single-wave: cheap)

    // ---- P1: Y transform, then chroma transform (b>=4 duplicates b-4) ----
    jpeg_block(y, QS[0], r);

    {
        const int ch = (b >> 1) & 1;     // lanes 4..7 mirror 0..3
        const int cblk = b & 1;
        float c[8];
#pragma unroll
        for (int j = 0; j < 8; ++j) c[j] = PL[ch][r][cblk * 8 + j];
        jpeg_block(c, QS[1], r);
        if (b < 4) {
#pragma unroll
            for (int j = 0; j < 8; ++j) CL[ch][r][cblk * 8 + j] = c[j];
        }
    }
    __syncthreads();   // CL ready

    // ---- P2: combine + store ----
    {
        const int prow = br * 4 + (r >> 1);
        const int pc = bc * 4;
        float cbv[4], crv[4];
#pragma unroll
        for (int jj = 0; jj < 4; ++jj) {
            cbv[jj] = CL[0][prow][pc + jj];
            crv[jj] = CL[1][prow][pc + jj];
        }
        float oR[8], oG[8], oB[8];
#pragma unroll
        for (int j = 0; j < 8; ++j) {
            float cb = cbv[j >> 1], cr = crv[j >> 1];
            float yv = y[j] + 128.0f;
            float R = yv + 1.402f * cr;
            float G = yv - 0.344136f * cb - 0.714136f * cr;
            float B = yv + 1.772f * cb;
            oR[j] = fminf(fmaxf(R, 0.0f), 255.0f) * (1.0f / 255.0f);
            oG[j] = fminf(fmaxf(G, 0.0f), 255.0f) * (1.0f / 255.0f);
            oB[j] = fminf(fmaxf(B, 0.0f), 255.0f) * (1.0f / 255.0f);
        }
        float* p = dst + (size_t)py * 512 + px;
        *(float4*)(p)                 = make_float4(oR[0], oR[1], oR[2], oR[3]);
        *(float4*)(p + 4)             = make_float4(oR[4], oR[5], oR[6], oR[7]);
        *(float4*)(p + plane)         = make_float4(oG[0], oG[1], oG[2], oG[3]);
        *(float4*)(p + plane + 4)     = make_float4(oG[4], oG[5], oG[6], oG[7]);
        *(float4*)(p + 2 * plane)     = make_float4(oB[0], oB[1], oB[2], oB[3]);
        *(float4*)(p + 2 * plane + 4) = make_float4(oB[4], oB[5], oB[6], oB[7]);
    }
}

extern "C" void kernel_launch(void* const* d_in, const int* in_sizes, int n_in,
                              void* d_out, int out_size, void* d_ws, size_t ws_size,
                              hipStream_t stream) {
    const float* x = (const float*)d_in[0];
    float* out = (float*)d_out;
    dim3 grid(512, 16);   // 32x16 strips of 16x32 px per image, 16 images
    dim3 block(64);
    diffjpeg_kernel<<<grid, block, 0, stream>>>(x, out);
}

// Round 8
// 24.232 us; speedup vs baseline: 1.1292x; 1.0266x over previous
//
#include <hip/hip_runtime.h>

// DiffJPEG fused, v8: two fully-independent waves per 128-thread block.
// Each wave = 16x32 px strip (v7 structure): 8 Y blocks + 2 Cb + 2 Cr
// (chroma duplicated on lane b>=4 for a uniform instruction stream).
// No mid-kernel __syncthreads: waves are self-contained; intra-wave LDS
// ordering via wave-synchronous lgkmcnt fences. Blocks of 2 waves dodge the
// 16-workgroup/CU cap -> up to 24 waves/CU (vs 16 for 1-wave blocks).

__device__ constexpr float YTAB8[8][8] = {   // = _Y transposed (Y_TABLE)
    {16, 12, 14, 14, 18, 24, 49, 72},
    {11, 12, 13, 17, 22, 35, 64, 92},
    {10, 14, 16, 22, 37, 55, 78, 95},
    {16, 19, 24, 29, 56, 64, 87, 98},
    {24, 26, 40, 51, 68, 81, 103, 112},
    {40, 58, 57, 87, 109, 104, 121, 100},
    {51, 60, 69, 80, 103, 113, 120, 103},
    {61, 55, 56, 62, 77, 92, 101, 99}};

__device__ constexpr float CTAB8[8][8] = {
    {17, 18, 24, 47, 99, 99, 99, 99},
    {18, 21, 26, 66, 99, 99, 99, 99},
    {24, 26, 56, 99, 99, 99, 99, 99},
    {47, 66, 99, 99, 99, 99, 99, 99},
    {99, 99, 99, 99, 99, 99, 99, 99},
    {99, 99, 99, 99, 99, 99, 99, 99},
    {99, 99, 99, 99, 99, 99, 99, 99},
    {99, 99, 99, 99, 99, 99, 99, 99}};

#define C1f 0.9807852804032304f
#define C2f 0.9238795325112867f
#define C3f 0.8314696123025452f
#define C4f 0.7071067811865476f
#define C5f 0.5555702330196022f
#define C6f 0.3826834323650898f
#define C7f 0.1950903220161283f

__device__ __forceinline__ void dct8(float y[8]) {
    float e0=y[0]+y[7], e1=y[1]+y[6], e2=y[2]+y[5], e3=y[3]+y[4];
    float o0=y[0]-y[7], o1=y[1]-y[6], o2=y[2]-y[5], o3=y[3]-y[4];
    float t0=e0+e3, t1=e1+e2, d0=e0-e3, d1=e1-e2;
    y[0]=t0+t1; y[4]=(t0-t1)*C4f;
    y[2]=d0*C2f+d1*C6f; y[6]=d0*C6f-d1*C2f;
    y[1]=o0*C1f+o1*C3f+o2*C5f+o3*C7f;
    y[3]=o0*C3f-o1*C7f-o2*C1f-o3*C5f;
    y[5]=o0*C5f-o1*C1f+o2*C7f+o3*C3f;
    y[7]=o0*C7f-o1*C5f+o2*C3f-o3*C1f;
}

__device__ __forceinline__ void idct8(float y[8]) {
    float a=y[4]*C4f, p=y[0]+a, m=y[0]-a;
    float q=y[2]*C2f+y[6]*C6f, w=y[2]*C6f-y[6]*C2f;
    float E0=p+q, E1=m+w, E2=m-w, E3=p-q;
    float O0=y[1]*C1f+y[3]*C3f+y[5]*C5f+y[7]*C7f;
    float O1=y[1]*C3f-y[3]*C7f-y[5]*C1f-y[7]*C5f;
    float O2=y[1]*C5f-y[3]*C1f+y[5]*C7f+y[7]*C3f;
    float O3=y[1]*C7f-y[3]*C5f+y[5]*C3f-y[7]*C1f;
    y[0]=E0+O0; y[7]=E0-O0; y[1]=E1+O1; y[6]=E1-O1;
    y[2]=E2+O2; y[5]=E2-O2; y[3]=E3+O3; y[4]=E3-O3;
}

// 8x8 transpose across the 8 lanes (bits 3..5) holding one block.
__device__ __forceinline__ void transpose8(float y[8]) {
    const int lane = threadIdx.x & 63;
#pragma unroll
    for (int s = 1; s <= 4; s <<= 1) {
        const bool upper = (lane & (s << 3)) != 0;
#pragma unroll
        for (int j = 0; j < 8; ++j) {
            if ((j & s) == 0) {
                float a = y[j], b2 = y[j | s];
                float t = upper ? a : b2;
                t = __shfl_xor(t, s << 3, 64);
                if (upper) y[j] = t; else y[j | s] = t;
            }
        }
    }
}

// wave-synchronous LDS fence: prior ds_writes by this wave have landed;
// compiler may not move LDS ops across it. No inter-wave coupling.
__device__ __forceinline__ void wave_lds_fence() {
    __builtin_amdgcn_wave_barrier();
    asm volatile("s_waitcnt lgkmcnt(0)" ::: "memory");
    __builtin_amdgcn_wave_barrier();
}

// diff_round: hw v_fract (period-1 reduction) + hw v_sin/v_cos (revolutions),
// Chebyshev recurrence for harmonics 2..9.
__device__ __forceinline__ float diff_round_f(float x) {
    float f = __builtin_amdgcn_fractf(x);
    float sc = __builtin_amdgcn_sinf(f);
    float c1v = __builtin_amdgcn_cosf(f);
    float twoc = 2.0f * c1v;
    float sp = 0.0f, acc = 0.0f;
    const float coef[9] = {1.0f, -0.5f, 1.0f/3.0f, -0.25f, 0.2f,
                           -1.0f/6.0f, 1.0f/7.0f, -0.125f, 1.0f/9.0f};
#pragma unroll
    for (int n = 0; n < 9; ++n) {
        acc += coef[n] * sc;
        float sn = twoc * sc - sp;
        sp = sc; sc = sn;
    }
    return x - acc * 0.3183098861837907f;
}

__device__ __forceinline__ void jpeg_block(float y[8], const float* qs, int r) {
    dct8(y); transpose8(y); dct8(y);
#pragma unroll
    for (int j = 0; j < 8; ++j) {
        float s1v = qs[2 * (j * 8 + r)];
        float s2v = qs[2 * (j * 8 + r) + 1];
        y[j] = diff_round_f(y[j] * s1v) * s2v;
    }
    idct8(y); transpose8(y); idct8(y);
}

__global__ __launch_bounds__(128, 6) void diffjpeg_kernel(
        const float* __restrict__ x, float* __restrict__ out) {
    __shared__ float QS[2][128];        // shared by both waves (read-only after init)
    __shared__ float PL[2][2][8][17];   // [wave][ch][prow][pcol], stride 17
    __shared__ float CL[2][2][8][17];   // [wave][ch][prow][pcol]

    const int tid = threadIdx.x;        // 0..127

    // quant/dequant scales: s1 = 0.25*au*av/(T*0.1), s2 = 0.25*au*av*(T*0.1)
    {
        int type = tid >> 6;
        int k = tid & 63, u = k >> 3, v = k & 7;
        float t = (type ? CTAB8[u][v] : YTAB8[u][v]) * 0.1f;
        float aa = 0.25f * ((u == 0) ? C4f : 1.0f) * ((v == 0) ? C4f : 1.0f);
        QS[type][2 * k]     = aa / t;
        QS[type][2 * k + 1] = aa * t;
    }
    __syncthreads();   // only inter-wave coupling point (QS ready)

    const int wv = tid >> 6;            // wave within block
    const int lane = tid & 63;
    const int r = lane >> 3;            // row within block / transpose group
    const int b = lane & 7;             // Y block index within strip

    const int img = blockIdx.y;
    const int strip = blockIdx.x * 2 + wv;      // 0..511
    const int sy = (strip >> 4) * 16;
    const int sx = (strip & 15) * 32;
    const size_t plane = (size_t)512 * 512;
    const float* src = x + (size_t)img * 3 * plane;
    float* dst = out + (size_t)img * 3 * plane;

    const int br = b >> 2, bc = b & 3;
    const int py = sy + br * 8 + r;
    const int px = sx + bc * 8;

    // ---- P0: load one Y block-row (RGB), convert, pool ----
    float y[8];
    {
        const float* p = src + (size_t)py * 512 + px;
        float4 R0 = *(const float4*)(p);
        float4 R1 = *(const float4*)(p + 4);
        float4 G0 = *(const float4*)(p + plane);
        float4 G1 = *(const float4*)(p + plane + 4);
        float4 B0 = *(const float4*)(p + 2 * plane);
        float4 B1 = *(const float4*)(p + 2 * plane + 4);
        y[0] = 76.245f*R0.x + 149.685f*G0.x + 29.07f*B0.x - 128.0f;
        y[1] = 76.245f*R0.y + 149.685f*G0.y + 29.07f*B0.y - 128.0f;
        y[2] = 76.245f*R0.z + 149.685f*G0.z + 29.07f*B0.z - 128.0f;
        y[3] = 76.245f*R0.w + 149.685f*G0.w + 29.07f*B0.w - 128.0f;
        y[4] = 76.245f*R1.x + 149.685f*G1.x + 29.07f*B1.x - 128.0f;
        y[5] = 76.245f*R1.y + 149.685f*G1.y + 29.07f*B1.y - 128.0f;
        y[6] = 76.245f*R1.z + 149.685f*G1.z + 29.07f*B1.z - 128.0f;
        y[7] = 76.245f*R1.w + 149.685f*G1.w + 29.07f*B1.w - 128.0f;
        // horizontal pair sums -> chroma (coeff*255/4; +-128 shift cancels)
        float rh0=R0.x+R0.y, rh1=R0.z+R0.w, rh2=R1.x+R1.y, rh3=R1.z+R1.w;
        float gh0=G0.x+G0.y, gh1=G0.z+G0.w, gh2=G1.x+G1.y, gh3=G1.z+G1.w;
        float bh0=B0.x+B0.y, bh1=B0.z+B0.w, bh2=B1.x+B1.y, bh3=B1.z+B1.w;
        const float kbr = -10.75692f, kbg = -21.11808f, kbb = 31.875f;   // Cb
        const float krr =  31.875f,   krg = -26.69136f, krb = -5.18364f; // Cr
        float cb[4], cr[4];
        cb[0]=kbr*rh0+kbg*gh0+kbb*bh0; cb[1]=kbr*rh1+kbg*gh1+kbb*bh1;
        cb[2]=kbr*rh2+kbg*gh2+kbb*bh2; cb[3]=kbr*rh3+kbg*gh3+kbb*bh3;
        cr[0]=krr*rh0+krg*gh0+krb*bh0; cr[1]=krr*rh1+krg*gh1+krb*bh1;
        cr[2]=krr*rh2+krg*gh2+krb*bh2; cr[3]=krr*rh3+krg*gh3+krb*bh3;
#pragma unroll
        for (int k = 0; k < 4; ++k) {   // vertical pair add (rows r, r^1)
            cb[k] += __shfl_xor(cb[k], 8, 64);
            cr[k] += __shfl_xor(cr[k], 8, 64);
        }
        if (!(r & 1)) {
            const int prow = br * 4 + (r >> 1);
            const int pc = bc * 4;
#pragma unroll
            for (int k = 0; k < 4; ++k) {
                PL[wv][0][prow][pc + k] = cb[k];
                PL[wv][1][prow][pc + k] = cr[k];
            }
        }
    }
    wave_lds_fence();   // PL ready (intra-wave)

    // ---- P1: Y transform, then chroma transform (b>=4 duplicates b-4) ----
    jpeg_block(y, QS[0], r);

    {
        const int ch = (b >> 1) & 1;     // lanes 4..7 mirror 0..3
        const int cblk = b & 1;
        float c[8];
#pragma unroll
        for (int j = 0; j < 8; ++j) c[j] = PL[wv][ch][r][cblk * 8 + j];
        jpeg_block(c, QS[1], r);
        if (b < 4) {
#pragma unroll
            for (int j = 0; j < 8; ++j) CL[wv][ch][r][cblk * 8 + j] = c[j];
        }
    }
    wave_lds_fence();   // CL ready (intra-wave)

    // ---- P2: combine + store (per-plane to limit live registers) ----
    {
        const int prow = br * 4 + (r >> 1);
        const int pc = bc * 4;
        float cbv[4], crv[4];
#pragma unroll
        for (int jj = 0; jj < 4; ++jj) {
            cbv[jj] = CL[wv][0][prow][pc + jj];
            crv[jj] = CL[wv][1][prow][pc + jj];
        }
        float* p = dst + (size_t)py * 512 + px;
        float o[8];
#pragma unroll
        for (int j = 0; j < 8; ++j) {
            float v = (y[j] + 128.0f) + 1.402f * crv[j >> 1];
            o[j] = fminf(fmaxf(v, 0.0f), 255.0f) * (1.0f / 255.0f);
        }
        *(float4*)(p)     = make_float4(o[0], o[1], o[2], o[3]);
        *(float4*)(p + 4) = make_float4(o[4], o[5], o[6], o[7]);
#pragma unroll
        for (int j = 0; j < 8; ++j) {
            float v = (y[j] + 128.0f) - 0.344136f * cbv[j >> 1] - 0.714136f * crv[j >> 1];
            o[j] = fminf(fmaxf(v, 0.0f), 255.0f) * (1.0f / 255.0f);
        }
        *(float4*)(p + plane)     = make_float4(o[0], o[1], o[2], o[3]);
        *(float4*)(p + plane + 4) = make_float4(o[4], o[5], o[6], o[7]);
#pragma unroll
        for (int j = 0; j < 8; ++j) {
            float v = (y[j] + 128.0f) + 1.772f * cbv[j >> 1];
            o[j] = fminf(fmaxf(v, 0.0f), 255.0f) * (1.0f / 255.0f);
        }
        *(float4*)(p + 2 * plane)     = make_float4(o[0], o[1], o[2], o[3]);
        *(float4*)(p + 2 * plane + 4) = make_float4(o[4], o[5], o[6], o[7]);
    }
}

extern "C" void kernel_launch(void* const* d_in, const int* in_sizes, int n_in,
                              void* d_out, int out_size, void* d_ws, size_t ws_size,
                              hipStream_t stream) {
    const float* x = (const float*)d_in[0];
    float* out = (float*)d_out;
    dim3 grid(256, 16);   // 2 strips of 16x32 px per block, 512 strips per image
    dim3 block(128);
    diffjpeg_kernel<<<grid, block, 0, stream>>>(x, out);
}